// Round 13
// baseline (101.133 us; speedup 1.0000x reference)
//
#include <hip/hip_runtime.h>
#include <hip/hip_bf16.h>

#define H_ 256
#define W_ 256
#define C_ 128
#define NBPOS 1024   // N * 16 * 16 block positions
#define NACT 512

typedef __bf16 bf16x8 __attribute__((ext_vector_type(8)));
typedef float f32x4 __attribute__((ext_vector_type(4)));

// workspace layout (bytes)
#define SCALE_OFF 294912
#define SHIFT_OFF 295424
#define INACT_OFF 295936

// LDS-visibility barrier that does NOT drain vmcnt (R11-validated): in-flight
// global loads (weight prefetch + embedded copy stream) ride across it.
#define LGKM_BARRIER() do { \
  asm volatile("s_waitcnt lgkmcnt(0)" ::: "memory"); \
  __builtin_amdgcn_s_barrier(); \
  __builtin_amdgcn_sched_barrier(0); \
} while (0)

// Blocks 0..575: weight repack fp32 HWIO -> bf16 [tap][cin8][cout][8].
// Block 576: BN fold + inactive-block list (bitmap + compaction).
__global__ void prep_kernel(const float* __restrict__ w, const float* __restrict__ b,
                            const float* __restrict__ gamma, const float* __restrict__ beta,
                            const float* __restrict__ mean, const float* __restrict__ var,
                            const int* __restrict__ active,
                            __bf16* __restrict__ wprep, float* __restrict__ scale,
                            float* __restrict__ shift, int* __restrict__ inact) {
  int blk = blockIdx.x, tid = threadIdx.x;
  if (blk < 576) {
    int o = blk * 256 + tid;
    int j = o & 7, cout = (o >> 3) & 127, k8 = (o >> 10) & 15, tap = o >> 14;
    wprep[o] = (__bf16)w[((size_t)tap * 128 + k8 * 8 + j) * 128 + cout];
    return;
  }
  __shared__ unsigned mask[32];
  __shared__ int cnt;
  if (tid < 32) mask[tid] = 0u;
  if (tid == 0) cnt = 0;
  __syncthreads();
  for (int i = tid; i < NACT; i += 256) {
    int a = active[i];
    atomicOr(&mask[a >> 5], 1u << (a & 31));
  }
  if (tid < 128) {
    float s = gamma[tid] * rsqrtf(var[tid] + 1e-3f);
    scale[tid] = s;
    shift[tid] = (b[tid] - mean[tid]) * s + beta[tid];
  }
  __syncthreads();
  for (int p = tid; p < NBPOS; p += 256) {
    if (!((mask[p >> 5] >> (p & 31)) & 1u)) {
      int q = atomicAdd(&cnt, 1);
      inact[q] = p;   // order nondeterministic; disjoint coverage is what matters
    }
  }
}

// 512 wgs, one per active block (2 wg/CU at 72.5 KB LDS). Full-block conv
// (M=256, N=128, K=1152), BK=64 -> 18 K-steps, wave tile 4Mx8N. Embedded
// stream-copy of one inactive block (2 x 16B chunks per thread per step).
// Per-step issue order (in-order vmcnt discipline): ds_write(weights) ->
// weight prefetch -> copy stores -> copy loads, so the fast L2 weight wait
// never retires behind a ~900cy HBM copy-load. lgkm-only barriers throughout.
__global__ __launch_bounds__(256, 2) void main_kernel(
    const float* __restrict__ x, const __bf16* __restrict__ wprep,
    const float* __restrict__ scale, const float* __restrict__ shift,
    const int* __restrict__ active, const int* __restrict__ inact,
    float* __restrict__ y) {
  __shared__ unsigned char ldsA[324 * 128];   // 18x18 px x 64ch bf16 = 41472 B
  __shared__ unsigned char ldsB[2][16384];    // ping-pong 64k x 128cout bf16

  const int tid = threadIdx.x;
  const int lane = tid & 63;
  const int wid = tid >> 6;

  const int aid = active[blockIdx.x];
  const int bn = aid >> 8, by = (aid >> 4) & 15, bx = aid & 15;
  const int h0 = by * 16, w0 = bx * 16;
  const float* xb = x + (size_t)bn * (H_ * W_ * C_);

  // paired inactive block for the embedded copy
  const int cid = inact[blockIdx.x];
  const size_t cbase4 =
      ((((size_t)(cid >> 8) * H_ + ((cid >> 4) & 15) * 16) * W_ + (cid & 15) * 16) * C_) >> 2;
  const f32x4* __restrict__ xs = (const f32x4*)x;
  f32x4* __restrict__ ys = (f32x4*)y;
  f32x4 cbuf[4];                              // chunk c -> slot c&3 (static via STEP macro)
  auto cidx = [&](int c) -> size_t {          // 32 chunks x 256 thr x 16 B = 128 KB
    int lin = (c << 8) + tid;
    return cbase4 + (size_t)(lin >> 9) * (W_ * C_ / 4) + (lin & 511);
  };

  f32x4 acc[4][8];
  f32x4 zero = {0.f, 0.f, 0.f, 0.f};
#pragma unroll
  for (int i = 0; i < 4; ++i)
#pragma unroll
    for (int jj = 0; jj < 8; ++jj) acc[i][jj] = zero;

  const uint4* wp4 = (const uint4*)wprep;
  uint4 t[4];                                 // one BK=64 weight tile (16 KB) in flight
  auto load_t = [&](int v) {                  // tile for K-step v: tap=v%9, half=v/9
    int off = (v % 9) * 2048 + (v / 9) * 1024;
#pragma unroll
    for (int q = 0; q < 4; ++q) t[q] = wp4[off + q * 256 + tid];
  };
  auto stage = [&](int half) {                // 18x18 px x 64ch -> bf16 LDS, XOR-swizzled
    for (int u = tid; u < 324 * 8; u += 256) {
      int s = u >> 3, c8 = u & 7;
      int iy = s / 18, ix = s - iy * 18;
      int hs = h0 + iy, wsp = w0 + ix;
      float4 f0 = make_float4(0.f, 0.f, 0.f, 0.f), f1 = f0;
      if (hs < H_ && wsp < W_) {
        const float* p = xb + (size_t)(hs * W_ + wsp) * C_ + half * 64 + c8 * 8;
        f0 = *(const float4*)p;
        f1 = *(const float4*)(p + 4);
      }
      bf16x8 v;
      v[0] = (__bf16)f0.x; v[1] = (__bf16)f0.y; v[2] = (__bf16)f0.z; v[3] = (__bf16)f0.w;
      v[4] = (__bf16)f1.x; v[5] = (__bf16)f1.y; v[6] = (__bf16)f1.z; v[7] = (__bf16)f1.w;
      int lin = s * 128 + c8 * 16;
      *(bf16x8*)(&ldsA[lin ^ ((s & 7) << 4)]) = v;
    }
  };

  // prologue: weight tile 0 -> buf0; tile 1 in regs; copy chunks 0..3 in regs
  load_t(0);
  stage(0);
#pragma unroll
  for (int q = 0; q < 4; ++q) ((uint4*)ldsB[0])[q * 256 + tid] = t[q];
  load_t(1);
  cbuf[0] = xs[cidx(0)];
  cbuf[1] = xs[cidx(1)];
  cbuf[2] = xs[cidx(2)];
  cbuf[3] = xs[cidx(3)];
  LGKM_BARRIER();

  const int koff = (lane >> 4) * 16;          // 16B k-chunk within 32 channels
  const int colb = (lane & 15) * 16;
  const int krow = (lane >> 4) * 2048;        // k8-group row in ldsB (2 KB per k8)

// One K-step u (tap u%9, channel-half u/9). CUR/SA/SB are literals at each
// expansion -> all ldsB buffer and cbuf slot indices compile-time (rule #20).
#define STEP(u, CUR, SA, SB) do {                                              \
    if ((u) < 17) {                                                            \
      _Pragma("unroll")                                                        \
      for (int q = 0; q < 4; ++q)                                              \
        ((uint4*)ldsB[(CUR) ^ 1])[q * 256 + tid] = t[q];   /* tile u+1 */      \
    }                                                                          \
    if ((u) < 16) load_t((u) + 2);            /* oldest vmem in queue: L2 */   \
    if ((u) < 16) {                           /* store chunks 2u,2u+1 */       \
      __builtin_nontemporal_store(cbuf[SA], &ys[cidx(2 * (u))]);               \
      __builtin_nontemporal_store(cbuf[SB], &ys[cidx(2 * (u) + 1)]);           \
    }                                                                          \
    if ((u) < 14) {                           /* load chunks 2u+4,2u+5 */      \
      cbuf[SA] = xs[cidx(2 * (u) + 4)];                                        \
      cbuf[SB] = xs[cidx(2 * (u) + 5)];                                        \
    }                                                                          \
    {                                                                          \
      int tap = (u) % 9;                                                       \
      int dyv = tap / 3, dxv = tap - dyv * 3;                                  \
      _Pragma("unroll")                                                        \
      for (int kk = 0; kk < 2; ++kk) {                                         \
        bf16x8 a[4];                                                           \
        _Pragma("unroll")                                                      \
        for (int mi = 0; mi < 4; ++mi) {                                       \
          int srow = (wid * 4 + mi + dyv) * 18 + dxv + (lane & 15);            \
          int lin = srow * 128 + kk * 64 + koff;                               \
          a[mi] = *(const bf16x8*)(&ldsA[lin ^ ((srow & 7) << 4)]);            \
        }                                                                      \
        bf16x8 bfr[8];                                                         \
        _Pragma("unroll")                                                      \
        for (int nb = 0; nb < 8; ++nb)                                         \
          bfr[nb] = *(const bf16x8*)(&ldsB[CUR][kk * 8192 + krow + nb * 256 + colb]); \
        _Pragma("unroll")                                                      \
        for (int mi = 0; mi < 4; ++mi)                                         \
          _Pragma("unroll")                                                    \
          for (int nb = 0; nb < 8; ++nb)                                       \
            acc[mi][nb] = __builtin_amdgcn_mfma_f32_16x16x32_bf16(             \
                a[mi], bfr[nb], acc[mi][nb], 0, 0, 0);                         \
      }                                                                        \
    }                                                                          \
    LGKM_BARRIER();                                                            \
    if ((u) == 8) {                           /* switch ldsA to channel half 1 */ \
      stage(1);                                                                \
      LGKM_BARRIER();                                                          \
    }                                                                          \
  } while (0)

  for (int up = 0; up < 9; ++up) {
    STEP(2 * up,     0, 0, 1);
    STEP(2 * up + 1, 1, 2, 3);
  }
#undef STEP

  // epilogue: BN + ReLU + scatter. D frag: col=lane&15, row=(lane>>4)*4+reg.
  // Plain (non-NT) stores: L2 write-combines the 4B scatter into full lines.
  const int colc = lane & 15;
  float sc[8], sh[8];
#pragma unroll
  for (int nb = 0; nb < 8; ++nb) {
    sc[nb] = scale[nb * 16 + colc];
    sh[nb] = shift[nb * 16 + colc];
  }
  float* yb = y + (((size_t)bn * H_ + h0) * W_ + w0) * C_;
#pragma unroll
  for (int mi = 0; mi < 4; ++mi) {
    int oy = wid * 4 + mi;
#pragma unroll
    for (int r = 0; r < 4; ++r) {
      int ox = (lane >> 4) * 4 + r;
      float* yr = yb + ((size_t)oy * W_ + ox) * C_;
#pragma unroll
      for (int nb = 0; nb < 8; ++nb) {
        float v = acc[mi][nb][r] * sc[nb] + sh[nb];
        yr[nb * 16 + colc] = fmaxf(v, 0.f);
      }
    }
  }
}

extern "C" void kernel_launch(void* const* d_in, const int* in_sizes, int n_in,
                              void* d_out, int out_size, void* d_ws, size_t ws_size,
                              hipStream_t stream) {
  const float* x     = (const float*)d_in[0];
  const float* w     = (const float*)d_in[1];
  const float* b     = (const float*)d_in[2];
  const float* gamma = (const float*)d_in[3];
  const float* beta  = (const float*)d_in[4];
  const float* mean  = (const float*)d_in[5];
  const float* var   = (const float*)d_in[6];
  const int*   act   = (const int*)d_in[7];
  float* y = (float*)d_out;
  char* ws = (char*)d_ws;
  __bf16* wprep = (__bf16*)ws;
  float* scale = (float*)(ws + SCALE_OFF);
  float* shift = (float*)(ws + SHIFT_OFF);
  int* inact = (int*)(ws + INACT_OFF);

  prep_kernel<<<dim3(577), dim3(256), 0, stream>>>(w, b, gamma, beta, mean, var, act,
                                                   wprep, scale, shift, inact);
  main_kernel<<<dim3(NACT), dim3(256), 0, stream>>>(x, wprep, scale, shift, act, inact, y);
}

// Round 14
// 81.819 us; speedup vs baseline: 1.2361x; 1.2361x over previous
//
#include <hip/hip_runtime.h>
#include <hip/hip_bf16.h>

#define H_ 256
#define W_ 256
#define C_ 128
#define NBPOS 1024   // N * 16 * 16 block positions
#define NACT 512

typedef __bf16 bf16x8 __attribute__((ext_vector_type(8)));
typedef float f32x4 __attribute__((ext_vector_type(4)));

// workspace layout (bytes)
#define SCALE_OFF 294912
#define SHIFT_OFF 295424
#define INACT_OFF 295936

// Blocks 0..575: weight repack fp32 HWIO -> bf16 [tap][cin8][cout][8].
// Block 576: BN fold + inactive-block list (bitmap + compaction).
__global__ void prep_kernel(const float* __restrict__ w, const float* __restrict__ b,
                            const float* __restrict__ gamma, const float* __restrict__ beta,
                            const float* __restrict__ mean, const float* __restrict__ var,
                            const int* __restrict__ active,
                            __bf16* __restrict__ wprep, float* __restrict__ scale,
                            float* __restrict__ shift, int* __restrict__ inact) {
  int blk = blockIdx.x, tid = threadIdx.x;
  if (blk < 576) {
    int o = blk * 256 + tid;
    int j = o & 7, cout = (o >> 3) & 127, k8 = (o >> 10) & 15, tap = o >> 14;
    wprep[o] = (__bf16)w[((size_t)tap * 128 + k8 * 8 + j) * 128 + cout];
    return;
  }
  __shared__ unsigned mask[32];
  __shared__ int cnt;
  if (tid < 32) mask[tid] = 0u;
  if (tid == 0) cnt = 0;
  __syncthreads();
  for (int i = tid; i < NACT; i += 256) {
    int a = active[i];
    atomicOr(&mask[a >> 5], 1u << (a & 31));
  }
  if (tid < 128) {
    float s = gamma[tid] * rsqrtf(var[tid] + 1e-3f);
    scale[tid] = s;
    shift[tid] = (b[tid] - mean[tid]) * s + beta[tid];
  }
  __syncthreads();
  for (int p = tid; p < NBPOS; p += 256) {
    if (!((mask[p >> 5] >> (p & 31)) & 1u)) {
      int q = atomicAdd(&cnt, 1);
      inact[q] = p;   // order nondeterministic; disjoint coverage is what matters
    }
  }
}

// ONE main kernel, 1536 wgs interleaved 2 conv : 1 copy (R8 structure — best
// measured at 75.3 us) with ONE change: the B weight tile is staged into LDS
// via global_load_lds (direct HBM/L2->LDS DMA, width=16). Removes per step:
// 2x16B register loads + 2 ds_writes + the vmcnt wait before them (+~32 VGPR)
// — the staging round-trip the GEMM ladder identifies as the 2-barrier-loop
// bottleneck (m93->m97: +69%). wprep is already bf16 and ldsB is linear
// tid*16, the exact pattern global_load_lds supports.
//   idx%3==2 -> copy wg: stream inactive block inact[idx/3] x->y (NT stores).
//   else     -> conv wg j=(idx/3)*2+(idx%3): M=128 half-block of active[j>>1].
// A patch: 10x18 px x 64ch bf16 LDS, XOR-swizzled. 39.4 KB LDS, 4 wg/CU.
__global__ __launch_bounds__(256, 4) void main_kernel(
    const float* __restrict__ x, const __bf16* __restrict__ wprep,
    const float* __restrict__ scale, const float* __restrict__ shift,
    const int* __restrict__ active, const int* __restrict__ inact,
    float* __restrict__ y) {
  __shared__ unsigned char ldsA[180 * 128];   // 10*18 px x 64ch bf16 = 23040 B
  __shared__ unsigned char ldsB[2][8192];     // ping-pong 32k x 128cout bf16

  const int idx = blockIdx.x;
  const int tid = threadIdx.x;

  if (idx % 3 == 2) {
    // ---- copy path: whole inactive block, no barriers, NT stores ----
    const int cid = inact[idx / 3];
    const int cn = cid >> 8, cy = (cid >> 4) & 15, cx = cid & 15;
    const size_t base4 = ((((size_t)cn * H_ + cy * 16) * W_ + cx * 16) * C_) >> 2;
    const f32x4* __restrict__ xs = (const f32x4*)x;
    f32x4* __restrict__ ys = (f32x4*)y;
#pragma unroll 4
    for (int i = 0; i < 32; ++i) {
      int lin = (i << 8) + tid;
      int row = lin >> 9, rem = lin & 511;
      size_t idx4 = base4 + (size_t)row * (W_ * C_ / 4) + rem;
      f32x4 v = xs[idx4];
      __builtin_nontemporal_store(v, &ys[idx4]);
    }
    return;
  }

  // ---- conv path ----
  const int j = (idx / 3) * 2 + (idx % 3);    // 0..1023
  const int lane = tid & 63;
  const int wid = tid >> 6;
  const int aid = active[j >> 1];
  const int mh = j & 1;                       // spatial half: rows 0-7 or 8-15
  const int bn = aid >> 8, by = (aid >> 4) & 15, bx = aid & 15;
  const int h0 = by * 16, w0 = bx * 16;
  const int hm = h0 + mh * 8;
  const float* xb = x + (size_t)bn * (H_ * W_ * C_);

  f32x4 acc[2][8];
  f32x4 zero = {0.f, 0.f, 0.f, 0.f};
#pragma unroll
  for (int i = 0; i < 2; ++i)
#pragma unroll
    for (int jj = 0; jj < 8; ++jj) acc[i][jj] = zero;

  // B tile u -> ldsB[buf] via direct global->LDS DMA. Each thread moves 16B
  // per call; LDS dest = wave-uniform base + lane*16 (HW rule). Two calls
  // cover the 8 KB tile: bytes [0,4096) and [4096,8192).
  auto gload_tile = [&](int u, int buf) {
    int ks = u % 18, h = u / 18;
    int tile = ((ks >> 1) << 2) + (h << 1) + (ks & 1);
    const __bf16* g0 = wprep + (size_t)tile * 4096 + (size_t)tid * 8;
    const __bf16* g1 = g0 + 2048;
    void* l0 = (void*)(ldsB[buf] + wid * 1024);
    void* l1 = (void*)(ldsB[buf] + 4096 + wid * 1024);
    __builtin_amdgcn_global_load_lds(
        (const __attribute__((address_space(1))) void*)g0,
        (__attribute__((address_space(3))) void*)l0, 16, 0, 0);
    __builtin_amdgcn_global_load_lds(
        (const __attribute__((address_space(1))) void*)g1,
        (__attribute__((address_space(3))) void*)l1, 16, 0, 0);
  };
  auto stage = [&](int half) {                // 10x18 px x 64ch -> bf16 LDS, XOR-swizzled
    for (int u = tid; u < 180 * 8; u += 256) {
      int s = u >> 3, c8 = u & 7;             // s = pr*18 + col
      int pr = s / 18, col = s - pr * 18;
      int hs = hm + pr, wsp = w0 + col;
      float4 f0 = make_float4(0.f, 0.f, 0.f, 0.f), f1 = f0;
      if (hs < H_ && wsp < W_) {
        const float* p = xb + (size_t)(hs * W_ + wsp) * C_ + half * 64 + c8 * 8;
        f0 = *(const float4*)p;
        f1 = *(const float4*)(p + 4);
      }
      bf16x8 v;
      v[0] = (__bf16)f0.x; v[1] = (__bf16)f0.y; v[2] = (__bf16)f0.z; v[3] = (__bf16)f0.w;
      v[4] = (__bf16)f1.x; v[5] = (__bf16)f1.y; v[6] = (__bf16)f1.z; v[7] = (__bf16)f1.w;
      int lin = s * 128 + c8 * 16;
      *(bf16x8*)(&ldsA[lin ^ ((s & 7) << 4)]) = v;
    }
  };

  // prologue: issue B tile 0 DMA, stage patch half 0, drain everything once
  gload_tile(0, 0);
  stage(0);
  __syncthreads();

  const int koff = (lane >> 4) * 16;          // 16B k-chunk within 32 channels
  const int colb = (lane & 15) * 16;
  const int krow = (lane >> 4) * 2048;

  for (int u = 0; u < 36; ++u) {
    int cur = u & 1;
    if (u < 35) gload_tile(u + 1, cur ^ 1);   // DMA next tile; lands during this step

    int ks = u % 18;
    int tap = ks >> 1, kch = ks & 1;
    int dyv = tap / 3, dxv = tap - dyv * 3;

    bf16x8 a[2];
#pragma unroll
    for (int mi = 0; mi < 2; ++mi) {
      int srow = (wid * 2 + mi + dyv) * 18 + dxv + (lane & 15);
      int lin = srow * 128 + kch * 64 + koff;
      a[mi] = *(const bf16x8*)(&ldsA[lin ^ ((srow & 7) << 4)]);
    }
    bf16x8 bfr[8];
#pragma unroll
    for (int nb = 0; nb < 8; ++nb)
      bfr[nb] = *(const bf16x8*)(&ldsB[cur][krow + nb * 256 + colb]);
#pragma unroll
    for (int mi = 0; mi < 2; ++mi)
#pragma unroll
      for (int nb = 0; nb < 8; ++nb)
        acc[mi][nb] = __builtin_amdgcn_mfma_f32_16x16x32_bf16(a[mi], bfr[nb], acc[mi][nb], 0, 0, 0);

    __syncthreads();                          // drains the 2 DMA ops + LDS reads

    if (u == 17) {                            // re-stage ldsA with channel half 1
      stage(1);
      __syncthreads();
    }
  }

  // epilogue: BN + ReLU + scatter (NT stores: R8's clean 135 MB WRITE_SIZE).
  // D frag: col=lane&15, row=(lane>>4)*4+reg
  const int colc = lane & 15;
  float sc[8], sh[8];
#pragma unroll
  for (int nb = 0; nb < 8; ++nb) {
    sc[nb] = scale[nb * 16 + colc];
    sh[nb] = shift[nb * 16 + colc];
  }
  float* yb = y + (((size_t)bn * H_ + hm) * W_ + w0) * C_;
#pragma unroll
  for (int mi = 0; mi < 2; ++mi) {
    int oy = wid * 2 + mi;                    // row within this wg's 8-row half
#pragma unroll
    for (int r = 0; r < 4; ++r) {
      int ox = (lane >> 4) * 4 + r;
      float* yr = yb + ((size_t)oy * W_ + ox) * C_;
#pragma unroll
      for (int nb = 0; nb < 8; ++nb) {
        float v = acc[mi][nb][r] * sc[nb] + sh[nb];
        __builtin_nontemporal_store(fmaxf(v, 0.f), &yr[nb * 16 + colc]);
      }
    }
  }
}

extern "C" void kernel_launch(void* const* d_in, const int* in_sizes, int n_in,
                              void* d_out, int out_size, void* d_ws, size_t ws_size,
                              hipStream_t stream) {
  const float* x     = (const float*)d_in[0];
  const float* w     = (const float*)d_in[1];
  const float* b     = (const float*)d_in[2];
  const float* gamma = (const float*)d_in[3];
  const float* beta  = (const float*)d_in[4];
  const float* mean  = (const float*)d_in[5];
  const float* var   = (const float*)d_in[6];
  const int*   act   = (const int*)d_in[7];
  float* y = (float*)d_out;
  char* ws = (char*)d_ws;
  __bf16* wprep = (__bf16*)ws;
  float* scale = (float*)(ws + SCALE_OFF);
  float* shift = (float*)(ws + SHIFT_OFF);
  int* inact = (int*)(ws + INACT_OFF);

  prep_kernel<<<dim3(577), dim3(256), 0, stream>>>(w, b, gamma, beta, mean, var, act,
                                                   wprep, scale, shift, inact);
  main_kernel<<<dim3(1536), dim3(256), 0, stream>>>(x, wprep, scale, shift, act, inact, y);
}

// Round 15
// 79.287 us; speedup vs baseline: 1.2755x; 1.0319x over previous
//
#include <hip/hip_runtime.h>
#include <hip/hip_bf16.h>

#define H_ 256
#define W_ 256
#define C_ 128
#define NBPOS 1024   // N * 16 * 16 block positions
#define NACT 512

typedef __bf16 bf16x8 __attribute__((ext_vector_type(8)));
typedef float f32x4 __attribute__((ext_vector_type(4)));

// workspace layout (bytes)
#define SCALE_OFF 294912
#define SHIFT_OFF 295424
#define INACT_OFF 295936

// Blocks 0..575: weight repack fp32 HWIO -> bf16 [tap][cin8][cout][8].
// Block 576: BN fold + inactive-block list (bitmap + compaction).
__global__ void prep_kernel(const float* __restrict__ w, const float* __restrict__ b,
                            const float* __restrict__ gamma, const float* __restrict__ beta,
                            const float* __restrict__ mean, const float* __restrict__ var,
                            const int* __restrict__ active,
                            __bf16* __restrict__ wprep, float* __restrict__ scale,
                            float* __restrict__ shift, int* __restrict__ inact) {
  int blk = blockIdx.x, tid = threadIdx.x;
  if (blk < 576) {
    int o = blk * 256 + tid;
    int j = o & 7, cout = (o >> 3) & 127, k8 = (o >> 10) & 15, tap = o >> 14;
    wprep[o] = (__bf16)w[((size_t)tap * 128 + k8 * 8 + j) * 128 + cout];
    return;
  }
  __shared__ unsigned mask[32];
  __shared__ int cnt;
  if (tid < 32) mask[tid] = 0u;
  if (tid == 0) cnt = 0;
  __syncthreads();
  for (int i = tid; i < NACT; i += 256) {
    int a = active[i];
    atomicOr(&mask[a >> 5], 1u << (a & 31));
  }
  if (tid < 128) {
    float s = gamma[tid] * rsqrtf(var[tid] + 1e-3f);
    scale[tid] = s;
    shift[tid] = (b[tid] - mean[tid]) * s + beta[tid];
  }
  __syncthreads();
  for (int p = tid; p < NBPOS; p += 256) {
    if (!((mask[p >> 5] >> (p & 31)) & 1u)) {
      int q = atomicAdd(&cnt, 1);
      inact[q] = p;   // order nondeterministic; disjoint coverage is what matters
    }
  }
}

// ONE main kernel, 1536 wgs interleaved 2 conv : 1 copy (R8's proven mix) with
// the conv K-loop made BARRIER-FREE: ldsB is gone — B fragments are read
// directly from wprep (bf16, 8 KB/step, identical addresses across all waves
// -> L1-resident and shared by every conv wg on the CU). Only ldsA remains
// (23 KB, XOR-swizzled); 3 __syncthreads in the whole conv (around the two
// A-stage passes). With no per-step fences the compiler software-pipelines
// B-loads across MFMAs freely (the 36-barrier convoy was the measured pacer:
// 4 structural nulls at MfmaUtil 14%).
//   idx%3==2 -> copy wg: stream inactive block inact[idx/3] x->y (plain loads
//               keep x L3-warm, NT stores).
//   else     -> conv wg j=(idx/3)*2+(idx%3): M=128 half-block of active[j>>1].
__global__ __launch_bounds__(256, 4) void main_kernel(
    const float* __restrict__ x, const __bf16* __restrict__ wprep,
    const float* __restrict__ scale, const float* __restrict__ shift,
    const int* __restrict__ active, const int* __restrict__ inact,
    float* __restrict__ y) {
  __shared__ unsigned char ldsA[180 * 128];   // 10*18 px x 64ch bf16 = 23040 B

  const int idx = blockIdx.x;
  const int tid = threadIdx.x;

  if (idx % 3 == 2) {
    // ---- copy path: whole inactive block, no barriers, NT stores ----
    const int cid = inact[idx / 3];
    const int cn = cid >> 8, cy = (cid >> 4) & 15, cx = cid & 15;
    const size_t base4 = ((((size_t)cn * H_ + cy * 16) * W_ + cx * 16) * C_) >> 2;
    const f32x4* __restrict__ xs = (const f32x4*)x;
    f32x4* __restrict__ ys = (f32x4*)y;
#pragma unroll 4
    for (int i = 0; i < 32; ++i) {
      int lin = (i << 8) + tid;
      int row = lin >> 9, rem = lin & 511;
      size_t idx4 = base4 + (size_t)row * (W_ * C_ / 4) + rem;
      f32x4 v = xs[idx4];
      __builtin_nontemporal_store(v, &ys[idx4]);
    }
    return;
  }

  // ---- conv path ----
  const int j = (idx / 3) * 2 + (idx % 3);    // 0..1023
  const int lane = tid & 63;
  const int wid = tid >> 6;
  const int aid = active[j >> 1];
  const int mh = j & 1;                       // spatial half: rows 0-7 or 8-15
  const int bn = aid >> 8, by = (aid >> 4) & 15, bx = aid & 15;
  const int h0 = by * 16, w0 = bx * 16;
  const int hm = h0 + mh * 8;
  const float* xb = x + (size_t)bn * (H_ * W_ * C_);

  f32x4 acc[2][8];
  f32x4 zero = {0.f, 0.f, 0.f, 0.f};
#pragma unroll
  for (int i = 0; i < 2; ++i)
#pragma unroll
    for (int jj = 0; jj < 8; ++jj) acc[i][jj] = zero;

  const bf16x8* __restrict__ wq = (const bf16x8*)wprep;  // 16B fragment units
  const int koff = (lane >> 4) * 16;          // 16B k-chunk within 32 channels
  // B-frag base (16B units): tile*512 + (lane>>4)*128 + (lane&15)
  const int sbl = ((lane >> 4) << 7) + (lane & 15);

  auto stage = [&](int half) {                // 10x18 px x 64ch -> bf16 LDS, XOR-swizzled
    for (int u = tid; u < 180 * 8; u += 256) {
      int s = u >> 3, c8 = u & 7;             // s = pr*18 + col
      int pr = s / 18, col = s - pr * 18;
      int hs = hm + pr, wsp = w0 + col;
      float4 f0 = make_float4(0.f, 0.f, 0.f, 0.f), f1 = f0;
      if (hs < H_ && wsp < W_) {
        const float* p = xb + (size_t)(hs * W_ + wsp) * C_ + half * 64 + c8 * 8;
        f0 = *(const float4*)p;
        f1 = *(const float4*)(p + 4);
      }
      bf16x8 v;
      v[0] = (__bf16)f0.x; v[1] = (__bf16)f0.y; v[2] = (__bf16)f0.z; v[3] = (__bf16)f0.w;
      v[4] = (__bf16)f1.x; v[5] = (__bf16)f1.y; v[6] = (__bf16)f1.z; v[7] = (__bf16)f1.w;
      int lin = s * 128 + c8 * 16;
      *(bf16x8*)(&ldsA[lin ^ ((s & 7) << 4)]) = v;
    }
  };

  for (int half = 0; half < 2; ++half) {
    if (half) __syncthreads();                // all waves done reading half 0
    stage(half);
    __syncthreads();                          // ldsA staged; K-loop is fence-free

#pragma unroll 2
    for (int ks = 0; ks < 18; ++ks) {
      int tap = ks >> 1, kch = ks & 1;
      int dyv = tap / 3, dxv = tap - dyv * 3;
      int tile = tap * 4 + half * 2 + kch;

      bf16x8 a[2];
#pragma unroll
      for (int mi = 0; mi < 2; ++mi) {
        int srow = (wid * 2 + mi + dyv) * 18 + dxv + (lane & 15);
        int lin = srow * 128 + kch * 64 + koff;
        a[mi] = *(const bf16x8*)(&ldsA[lin ^ ((srow & 7) << 4)]);
      }
      bf16x8 bfr[8];
      int sb = tile * 512 + sbl;
#pragma unroll
      for (int nb = 0; nb < 8; ++nb)
        bfr[nb] = wq[sb + nb * 16];           // L1-resident, shared across waves/wgs
#pragma unroll
      for (int mi = 0; mi < 2; ++mi)
#pragma unroll
        for (int nb = 0; nb < 8; ++nb)
          acc[mi][nb] = __builtin_amdgcn_mfma_f32_16x16x32_bf16(a[mi], bfr[nb], acc[mi][nb], 0, 0, 0);
    }
  }

  // epilogue: BN + ReLU + scatter (NT stores: R8's clean 135 MB WRITE_SIZE).
  // D frag: col=lane&15, row=(lane>>4)*4+reg
  const int colc = lane & 15;
  float sc[8], sh[8];
#pragma unroll
  for (int nb = 0; nb < 8; ++nb) {
    sc[nb] = scale[nb * 16 + colc];
    sh[nb] = shift[nb * 16 + colc];
  }
  float* yb = y + (((size_t)bn * H_ + hm) * W_ + w0) * C_;
#pragma unroll
  for (int mi = 0; mi < 2; ++mi) {
    int oy = wid * 2 + mi;                    // row within this wg's 8-row half
#pragma unroll
    for (int r = 0; r < 4; ++r) {
      int ox = (lane >> 4) * 4 + r;
      float* yr = yb + ((size_t)oy * W_ + ox) * C_;
#pragma unroll
      for (int nb = 0; nb < 8; ++nb) {
        float v = acc[mi][nb][r] * sc[nb] + sh[nb];
        __builtin_nontemporal_store(fmaxf(v, 0.f), &yr[nb * 16 + colc]);
      }
    }
  }
}

extern "C" void kernel_launch(void* const* d_in, const int* in_sizes, int n_in,
                              void* d_out, int out_size, void* d_ws, size_t ws_size,
                              hipStream_t stream) {
  const float* x     = (const float*)d_in[0];
  const float* w     = (const float*)d_in[1];
  const float* b     = (const float*)d_in[2];
  const float* gamma = (const float*)d_in[3];
  const float* beta  = (const float*)d_in[4];
  const float* mean  = (const float*)d_in[5];
  const float* var   = (const float*)d_in[6];
  const int*   act   = (const int*)d_in[7];
  float* y = (float*)d_out;
  char* ws = (char*)d_ws;
  __bf16* wprep = (__bf16*)ws;
  float* scale = (float*)(ws + SCALE_OFF);
  float* shift = (float*)(ws + SHIFT_OFF);
  int* inact = (int*)(ws + INACT_OFF);

  prep_kernel<<<dim3(577), dim3(256), 0, stream>>>(w, b, gamma, beta, mean, var, act,
                                                   wprep, scale, shift, inact);
  main_kernel<<<dim3(1536), dim3(256), 0, stream>>>(x, wprep, scale, shift, act, inact, y);
}